// Round 9
// baseline (215.364 us; speedup 1.0000x reference)
//
#include <hip/hip_runtime.h>

#define T_TOK  16384
#define IN_F   1024
#define OUT_F  1024
#define NE     8

typedef __bf16 bf16;
typedef bf16  bf16x4 __attribute__((ext_vector_type(4)));
typedef bf16  bf16x8 __attribute__((ext_vector_type(8)));
typedef float f32x4  __attribute__((ext_vector_type(4)));

// ---------------------------------------------------------------------------
// Shared GEMM geometry. 256x256 tile, BK=64, 8 waves (2M x 4N).
// ---------------------------------------------------------------------------
#define BM 256
#define BN 256
#define BK 64
#define GTHREADS 512
#define NBLOCKS 256
#define KCH (IN_F / BK)      // 16 K-chunks per tile
#define SP_BLOCKS 112        // 28 surplus tiles x 4 K-slices (max)

// ---------------------------------------------------------------------------
// Pass 1: fp32 -> bf16 convert (bf16x8 = 16B writes) + zero-fill ONLY the
// surplus rows [R64, T_TOK).
// ---------------------------------------------------------------------------
#define CVT_THREADS 256
#define NX8 (T_TOK * IN_F / 8)
#define NW8 (NE * OUT_F * IN_F / 8)
#define NCVT8 (NX8 + NW8)

__global__ __launch_bounds__(CVT_THREADS)
void cvt_and_zero(const float* __restrict__ x, const float* __restrict__ w,
                  bf16* __restrict__ xb, bf16* __restrict__ wb,
                  const int* __restrict__ seg_lens, float* __restrict__ out)
{
    int r64 = T_TOK;
    {
        int slots = 0, start = 0;
        #pragma unroll
        for (int e = 0; e < NE; ++e) {
            int len = seg_lens[e];
            int nt  = (len + BM - 1) >> 8;
            if (slots <= 64 && slots + nt > 64) {
                r64 = start + (64 - slots) * BM;
            }
            slots += nt;
            start += len;
        }
    }
    const int zero8 = (T_TOK - r64) * (OUT_F / 8);
    const int zb8   = r64 * (OUT_F / 8);
    const int tot   = NCVT8 + zero8;

    for (int i = blockIdx.x * CVT_THREADS + threadIdx.x; i < tot;
         i += gridDim.x * CVT_THREADS) {
        if (i < NCVT8) {
            const bool isx = (i < NX8);
            const int  j   = isx ? i : i - NX8;
            f32x4 v0 = isx ? ((const f32x4*)x)[2*j]   : ((const f32x4*)w)[2*j];
            f32x4 v1 = isx ? ((const f32x4*)x)[2*j+1] : ((const f32x4*)w)[2*j+1];
            bf16x8 h;
            #pragma unroll
            for (int k = 0; k < 4; ++k) { h[k] = (bf16)v0[k]; h[4+k] = (bf16)v1[k]; }
            if (isx) ((bf16x8*)xb)[j] = h;
            else     ((bf16x8*)wb)[j] = h;
        } else {
            f32x4 z = {0.f, 0.f, 0.f, 0.f};
            const int j = zb8 + (i - NCVT8);
            ((f32x4*)out)[2*j]   = z;
            ((f32x4*)out)[2*j+1] = z;
        }
    }
}

// ---------------------------------------------------------------------------
// Common helpers
// ---------------------------------------------------------------------------
__device__ __forceinline__ void gld_lds16(const bf16* g, bf16* l) {
    __builtin_amdgcn_global_load_lds(
        (const __attribute__((address_space(1))) void*)g,
        (__attribute__((address_space(3))) void*)l,
        16, 0, 0);
}

__device__ __forceinline__ void resolve_slot(const int* sl, int slot,
                                             int& e_sel, int& row0, int& rows)
{
    e_sel = -1; row0 = 0; rows = 0;
    int start = 0, acct = 0;
    #pragma unroll
    for (int e = 0; e < NE; ++e) {
        int len = sl[e];
        int nt  = (len + BM - 1) >> 8;
        if (e_sel < 0 && slot >= acct && slot < acct + nt) {
            e_sel = e;
            row0  = start + (slot - acct) * BM;
            int rm = start + len - row0;
            rows = rm < BM ? rm : BM;
        }
        acct  += nt;
        start += len;
    }
}

// ---------------------------------------------------------------------------
// Pass 2: MAIN kernel — 4-phase fine-interleaved K-step (T3) on top of r8's
// counted vmcnt (T4) + XOR read swizzle (T2, conflicts=0) + setprio (T5) +
// XCD-chunked tile swizzle (T1).
// Per step: 4 phases x {2 gld_lds issue | ds_read subtile -> s_barrier ->
// lgkmcnt(0)+sched_barrier -> setprio(1) 16xMFMA setprio(0) -> s_barrier}.
// Phase 0 carries the counted wait: vmcnt(2) (chunk-n's 8 loads done, the 2
// just-issued chunk-n+1 loads stay in flight). Never vmcnt(0) mid-loop.
// Buffer safety: reads of buf[cur] are lgkm-drained before phase 3's end
// barrier; writes into buf[cur] (step n+2) issue after it.
// ---------------------------------------------------------------------------
__global__ __launch_bounds__(GTHREADS)
void grouped_gemm_main(const bf16* __restrict__ xb,
                       const bf16* __restrict__ wb,
                       const int*  __restrict__ seg_lens,
                       float* __restrict__ out)
{
    __shared__ __align__(16) bf16 As[2][BM * BK];   // 2 x 32 KiB
    __shared__ __align__(16) bf16 Bs[2][BN * BK];   // 2 x 32 KiB

    // T1: XCD-chunked bijective swizzle (grid=256 = 8 XCD x 32). Blocks on
    // the same XCD (b%8 equal, round-robin dispatch) get 32 contiguous tiles
    // = 8 slots x 4 col-tiles -> x-panel + W-panel reuse within one L2.
    const int b    = blockIdx.x;
    const int tile = ((b & 7) << 5) | (b >> 3);
    const int slot = tile >> 2;
    const int col0 = (tile & 3) << 8;

    int sl[NE];
    #pragma unroll
    for (int e = 0; e < NE; ++e) sl[e] = seg_lens[e];

    int e_sel, row0, rows;
    resolve_slot(sl, slot, e_sel, row0, rows);
    if (e_sel < 0) return;   // unreachable (L >= 256), uniform safety exit

    const int tid  = threadIdx.x;
    const int lane = tid & 63;
    const int wave = tid >> 6;
    const int wr   = wave >> 2;
    const int wc   = wave & 3;
    const int quad = lane >> 4;
    const int l16  = lane & 15;
    const int rq   = lane >> 3;          // row within 8-row staging group
    const int q0   = wave * 4;
    const int swz8 = (l16 & 7) * 8;      // read-side swizzle (elements)

    // staging source column: inverse-swizzled so linear LDS dest ends up
    // holding the swizzled layout (rule #21 involution).
    const int ke_s = (((lane & 7) ^ rq) * 8);

    const bf16* wbase = wb + ((size_t)e_sel * OUT_F + (size_t)col0) * IN_F;

    const bf16* ga[4];
    const bf16* gb[4];
    #pragma unroll
    for (int i = 0; i < 4; ++i) {
        int q  = wave * 4 + i;
        int ra = row0 + q * 8 + rq;
        if (ra > T_TOK - 1) ra = T_TOK - 1;
        ga[i] = xb + (size_t)ra * IN_F + ke_s;
        gb[i] = wbase + (size_t)(q * 8 + rq) * IN_F + ke_s;
    }

    f32x4 acc[8][4] = {};

    // prologue: stage K-chunk 0 into buffer 0 (8 loads in flight)
    #pragma unroll
    for (int i = 0; i < 4; ++i) {
        gld_lds16(ga[i], &As[0][(q0 + i) * 512]);
        gld_lds16(gb[i], &Bs[0][(q0 + i) * 512]);
    }

    for (int n = 0; n < KCH; ++n) {
        const int  cur = n & 1;
        const int  nxt = cur ^ 1;
        const int  kn  = (n + 1) * BK;
        const bool pf  = (n + 1 < KCH);
        const bf16* Ab = &As[cur][0];
        const bf16* Bb = &Bs[cur][0];
        bf16x8 af[4], bfr[4];

        // ============ phase 0: kk=0, th=0 (reads AFTER barrier: new tile) ==
        if (pf) { gld_lds16(ga[0] + kn, &As[nxt][(q0 + 0) * 512]);
                  gld_lds16(gb[0] + kn, &Bs[nxt][(q0 + 0) * 512]); }
        if (pf) asm volatile("s_waitcnt vmcnt(2)" ::: "memory");
        else    asm volatile("s_waitcnt vmcnt(0)" ::: "memory");
        __builtin_amdgcn_s_barrier();          // chunk-n LDS data visible
        {
            const int ce = (quad * 8) ^ swz8;
            #pragma unroll
            for (int v = 0; v < 4; ++v)
                bfr[v] = *(const bf16x8*)(Bb + (wc * 64 + v * 16 + l16) * BK + ce);
            #pragma unroll
            for (int t = 0; t < 4; ++t)
                af[t] = *(const bf16x8*)(Ab + (wr * 128 + t * 16 + l16) * BK + ce);
        }
        asm volatile("s_waitcnt lgkmcnt(0)" ::: "memory");
        __builtin_amdgcn_sched_barrier(0);
        __builtin_amdgcn_s_setprio(1);
        #pragma unroll
        for (int t = 0; t < 4; ++t)
            #pragma unroll
            for (int v = 0; v < 4; ++v)
                acc[t][v] = __builtin_amdgcn_mfma_f32_16x16x32_bf16(
                    af[t], bfr[v], acc[t][v], 0, 0, 0);
        __builtin_amdgcn_s_setprio(0);
        __builtin_amdgcn_s_barrier();

        // ============ phase 1: kk=0, th=1 (bfr reused; af reads pre-barrier)
        if (pf) { gld_lds16(ga[1] + kn, &As[nxt][(q0 + 1) * 512]);
                  gld_lds16(gb[1] + kn, &Bs[nxt][(q0 + 1) * 512]); }
        {
            const int ce = (quad * 8) ^ swz8;
            #pragma unroll
            for (int t = 0; t < 4; ++t)
                af[t] = *(const bf16x8*)(Ab + (wr * 128 + 64 + t * 16 + l16) * BK + ce);
        }
        __builtin_amdgcn_s_barrier();
        asm volatile("s_waitcnt lgkmcnt(0)" ::: "memory");
        __builtin_amdgcn_sched_barrier(0);
        __builtin_amdgcn_s_setprio(1);
        #pragma unroll
        for (int t = 0; t < 4; ++t)
            #pragma unroll
            for (int v = 0; v < 4; ++v)
                acc[4 + t][v] = __builtin_amdgcn_mfma_f32_16x16x32_bf16(
                    af[t], bfr[v], acc[4 + t][v], 0, 0, 0);
        __builtin_amdgcn_s_setprio(0);
        __builtin_amdgcn_s_barrier();

        // ============ phase 2: kk=1, th=0 ==================================
        if (pf) { gld_lds16(ga[2] + kn, &As[nxt][(q0 + 2) * 512]);
                  gld_lds16(gb[2] + kn, &Bs[nxt][(q0 + 2) * 512]); }
        {
            const int ce = (32 + quad * 8) ^ swz8;
            #pragma unroll
            for (int v = 0; v < 4; ++v)
                bfr[v] = *(const bf16x8*)(Bb + (wc * 64 + v * 16 + l16) * BK + ce);
            #pragma unroll
            for (int t = 0; t < 4; ++t)
                af[t] = *(const bf16x8*)(Ab + (wr * 128 + t * 16 + l16) * BK + ce);
        }
        __builtin_amdgcn_s_barrier();
        asm volatile("s_waitcnt lgkmcnt(0)" ::: "memory");
        __builtin_amdgcn_sched_barrier(0);
        __builtin_amdgcn_s_setprio(1);
        #pragma unroll
        for (int t = 0; t < 4; ++t)
            #pragma unroll
            for (int v = 0; v < 4; ++v)
                acc[t][v] = __builtin_amdgcn_mfma_f32_16x16x32_bf16(
                    af[t], bfr[v], acc[t][v], 0, 0, 0);
        __builtin_amdgcn_s_setprio(0);
        __builtin_amdgcn_s_barrier();

        // ============ phase 3: kk=1, th=1 ==================================
        if (pf) { gld_lds16(ga[3] + kn, &As[nxt][(q0 + 3) * 512]);
                  gld_lds16(gb[3] + kn, &Bs[nxt][(q0 + 3) * 512]); }
        {
            const int ce = (32 + quad * 8) ^ swz8;
            #pragma unroll
            for (int t = 0; t < 4; ++t)
                af[t] = *(const bf16x8*)(Ab + (wr * 128 + 64 + t * 16 + l16) * BK + ce);
        }
        __builtin_amdgcn_s_barrier();
        asm volatile("s_waitcnt lgkmcnt(0)" ::: "memory");
        __builtin_amdgcn_sched_barrier(0);
        __builtin_amdgcn_s_setprio(1);
        #pragma unroll
        for (int t = 0; t < 4; ++t)
            #pragma unroll
            for (int v = 0; v < 4; ++v)
                acc[4 + t][v] = __builtin_amdgcn_mfma_f32_16x16x32_bf16(
                    af[t], bfr[v], acc[4 + t][v], 0, 0, 0);
        __builtin_amdgcn_s_setprio(0);
        __builtin_amdgcn_s_barrier();   // protects buf[cur] from step n+2 writes
    }

    // epilogue: C/D layout col=lane&15, row=quad*4+reg; plain store
    #pragma unroll
    for (int t = 0; t < 8; ++t) {
        #pragma unroll
        for (int r = 0; r < 4; ++r) {
            int row = wr * 128 + t * 16 + quad * 4 + r;
            if (row < rows) {
                size_t ob = (size_t)(row0 + row) * OUT_F + col0 + wc * 64;
                #pragma unroll
                for (int v = 0; v < 4; ++v)
                    out[ob + v * 16 + l16] = acc[t][v][r];
            }
        }
    }
}

// ---------------------------------------------------------------------------
// Pass 3: SURPLUS kernel — UNCHANGED from r7/r8 (K-split-by-4, single atomic
// flush per block onto pre-zeroed surplus rows). Linear LDS layout.
// ---------------------------------------------------------------------------
__global__ __launch_bounds__(GTHREADS)
void grouped_gemm_surplus(const bf16* __restrict__ xb,
                          const bf16* __restrict__ wb,
                          const int*  __restrict__ seg_lens,
                          float* __restrict__ out)
{
    __shared__ __align__(16) bf16 As[2][BM * BK];
    __shared__ __align__(16) bf16 Bs[2][BN * BK];

    const int tile   = NBLOCKS + (blockIdx.x >> 2);
    const int kslice = blockIdx.x & 3;

    int sl[NE];
    #pragma unroll
    for (int e = 0; e < NE; ++e) sl[e] = seg_lens[e];

    int n_slots = 0;
    #pragma unroll
    for (int e = 0; e < NE; ++e) n_slots += (sl[e] + BM - 1) >> 8;
    const int L = n_slots * (OUT_F / BN);
    if (tile >= L) return;    // block-uniform exit before any barrier

    const int slot = tile >> 2;
    const int col0 = (tile & 3) << 8;
    int e_sel, row0, rows;
    resolve_slot(sl, slot, e_sel, row0, rows);

    const int tid  = threadIdx.x;
    const int lane = tid & 63;
    const int wave = tid >> 6;
    const int wr   = wave >> 2;
    const int wc   = wave & 3;
    const int quad = lane >> 4;
    const int l16  = lane & 15;
    const int rq   = lane >> 3;
    const int ke   = (lane & 7) * 8;
    const int q0   = wave * 4;

    const bf16* wbase = wb + ((size_t)e_sel * OUT_F + (size_t)col0) * IN_F;

    const bf16* ga[4];
    const bf16* gb[4];
    #pragma unroll
    for (int i = 0; i < 4; ++i) {
        int q  = wave * 4 + i;
        int ra = row0 + q * 8 + rq;
        if (ra > T_TOK - 1) ra = T_TOK - 1;
        ga[i] = xb + (size_t)ra * IN_F + ke;
        gb[i] = wbase + (size_t)(q * 8 + rq) * IN_F + ke;
    }

    f32x4 acc[8][4] = {};

    const int kb0 = kslice * 4 * BK;

    #pragma unroll
    for (int i = 0; i < 4; ++i) {
        gld_lds16(ga[i] + kb0, &As[0][(q0 + i) * 512]);
        gld_lds16(gb[i] + kb0, &Bs[0][(q0 + i) * 512]);
    }
    __syncthreads();

    #pragma unroll
    for (int j = 0; j < 4; ++j) {       // static trip count: cur = j&1 static
        const int cur = j & 1;
        if (j < 3) {
            const int kn = kb0 + (j + 1) * BK;
            #pragma unroll
            for (int i = 0; i < 4; ++i) {
                gld_lds16(ga[i] + kn, &As[cur ^ 1][(q0 + i) * 512]);
                gld_lds16(gb[i] + kn, &Bs[cur ^ 1][(q0 + i) * 512]);
            }
        }

        #pragma unroll
        for (int kk = 0; kk < 2; ++kk) {
            bf16x8 af[8], bfr[4];
            #pragma unroll
            for (int t = 0; t < 8; ++t)
                af[t] = *(const bf16x8*)(
                    &As[cur][(wr * 128 + t * 16 + l16) * BK + kk * 32 + quad * 8]);
            #pragma unroll
            for (int v = 0; v < 4; ++v)
                bfr[v] = *(const bf16x8*)(
                    &Bs[cur][(wc * 64 + v * 16 + l16) * BK + kk * 32 + quad * 8]);
            #pragma unroll
            for (int t = 0; t < 8; ++t)
                #pragma unroll
                for (int v = 0; v < 4; ++v)
                    acc[t][v] = __builtin_amdgcn_mfma_f32_16x16x32_bf16(
                        af[t], bfr[v], acc[t][v], 0, 0, 0);
        }

        __syncthreads();
    }

    // single atomic flush (out pre-zeroed over surplus rows)
    #pragma unroll
    for (int t = 0; t < 8; ++t) {
        #pragma unroll
        for (int r = 0; r < 4; ++r) {
            int row = wr * 128 + t * 16 + quad * 4 + r;
            if (row < rows) {
                size_t ob = (size_t)(row0 + row) * OUT_F + col0 + wc * 64;
                #pragma unroll
                for (int v = 0; v < 4; ++v)
                    unsafeAtomicAdd(&out[ob + v * 16 + l16], acc[t][v][r]);
            }
        }
    }
}

// ---------------------------------------------------------------------------
// Fallback (ws too small): round-0 kernel — fp32 loads, in-loop cvt.
// ---------------------------------------------------------------------------
#define FBM 128
#define FBK 32
#define FTHREADS 256
#define FROW_SLOTS 136

__global__ __launch_bounds__(FTHREADS)
void grouped_gemm_f32io_bf16(const float* __restrict__ x,
                             const float* __restrict__ wgt,
                             const int*  __restrict__ seg_lens,
                             float* __restrict__ out)
{
    __shared__ __align__(16) bf16 Asf[FBM * FBK];
    __shared__ __align__(16) bf16 Bsf[FBM * FBK];

    const int m    = blockIdx.y;
    const int col0 = blockIdx.x * FBM;

    int e_sel = -1, row0 = 0, rows = 0;
    {
        int start = 0, acct = 0;
        #pragma unroll
        for (int e = 0; e < NE; ++e) {
            int len = seg_lens[e];
            int nt  = (len + FBM - 1) >> 7;
            if (e_sel < 0 && m >= acct && m < acct + nt) {
                e_sel = e;
                row0  = start + (m - acct) * FBM;
                int rem = start + len - row0;
                rows = rem < FBM ? rem : FBM;
            }
            acct  += nt;
            start += len;
        }
    }
    if (e_sel < 0) return;

    const int tid  = threadIdx.x;
    const int lane = tid & 63;
    const int wave = tid >> 6;
    const int wm   = (wave >> 1) * 64;
    const int wn   = (wave & 1) * 64;
    const int quad = lane >> 4;
    const int l16  = lane & 15;

    const float* wbase = wgt + ((size_t)e_sel * OUT_F + (size_t)col0) * IN_F;

    f32x4 acc[4][4] = {};

    for (int k0 = 0; k0 < IN_F; k0 += FBK) {
        f32x4 a_st[4], b_st[4];
        #pragma unroll
        for (int t = 0; t < 4; ++t) {
            int c  = t * FTHREADS + tid;
            int rg = row0 + (c >> 3);
            if (rg > T_TOK - 1) rg = T_TOK - 1;
            a_st[t] = *(const f32x4*)(x + (size_t)rg * IN_F + k0 + (c & 7) * 4);
            b_st[t] = *(const f32x4*)(wbase + (size_t)(c >> 3) * IN_F + k0 + (c & 7) * 4);
        }

        __syncthreads();

        #pragma unroll
        for (int t = 0; t < 4; ++t) {
            int c = t * FTHREADS + tid;
            bf16x4 ha, hb;
            #pragma unroll
            for (int j = 0; j < 4; ++j) { ha[j] = (bf16)a_st[t][j]; hb[j] = (bf16)b_st[t][j]; }
            *(bf16x4*)(&Asf[(c >> 3) * FBK + (c & 7) * 4]) = ha;
            *(bf16x4*)(&Bsf[(c >> 3) * FBK + (c & 7) * 4]) = hb;
        }
        __syncthreads();

        bf16x8 af[4], bfr[4];
        #pragma unroll
        for (int t = 0; t < 4; ++t)
            af[t] = *(const bf16x8*)(&Asf[(wm + t * 16 + l16) * FBK + quad * 8]);
        #pragma unroll
        for (int v = 0; v < 4; ++v)
            bfr[v] = *(const bf16x8*)(&Bsf[(wn + v * 16 + l16) * FBK + quad * 8]);

        #pragma unroll
        for (int t = 0; t < 4; ++t)
            #pragma unroll
            for (int v = 0; v < 4; ++v)
                acc[t][v] = __builtin_amdgcn_mfma_f32_16x16x32_bf16(
                    af[t], bfr[v], acc[t][v], 0, 0, 0);
    }

    #pragma unroll
    for (int t = 0; t < 4; ++t) {
        #pragma unroll
        for (int r = 0; r < 4; ++r) {
            int row = wm + t * 16 + quad * 4 + r;
            if (row < rows) {
                size_t ob = (size_t)(row0 + row) * OUT_F + col0;
                #pragma unroll
                for (int v = 0; v < 4; ++v)
                    out[ob + wn + v * 16 + l16] = acc[t][v][r];
            }
        }
    }
}

extern "C" void kernel_launch(void* const* d_in, const int* in_sizes, int n_in,
                              void* d_out, int out_size, void* d_ws, size_t ws_size,
                              hipStream_t stream) {
    const float* x   = (const float*)d_in[0];
    const float* wgt = (const float*)d_in[1];
    const int*   seg = (const int*)d_in[2];
    float* out = (float*)d_out;

    const size_t xbytes = (size_t)T_TOK * IN_F * sizeof(bf16);       // 33.55 MB
    const size_t wbytes = (size_t)NE * OUT_F * IN_F * sizeof(bf16);  // 16.78 MB

    if (ws_size >= xbytes + wbytes) {
        bf16* xb = (bf16*)d_ws;
        bf16* wb = (bf16*)((char*)d_ws + xbytes);
        cvt_and_zero<<<dim3(2048, 1, 1), dim3(CVT_THREADS, 1, 1), 0, stream>>>(
            x, wgt, xb, wb, seg, out);
        grouped_gemm_main<<<dim3(NBLOCKS, 1, 1), dim3(GTHREADS, 1, 1), 0, stream>>>(
            xb, wb, seg, out);
        grouped_gemm_surplus<<<dim3(SP_BLOCKS, 1, 1), dim3(GTHREADS, 1, 1), 0, stream>>>(
            xb, wb, seg, out);
    } else {
        grouped_gemm_f32io_bf16<<<dim3(OUT_F / FBM, FROW_SLOTS, 1),
                                  dim3(FTHREADS, 1, 1), 0, stream>>>(x, wgt, seg, out);
    }
}